// Round 6
// baseline (164.755 us; speedup 1.0000x reference)
//
#include <hip/hip_runtime.h>

// ---------------------------------------------------------------------------
// relu linear attention, bf16-MFMA
//   q,k,v: [B=4][H=8][128][8192] fp32   out: [B][128][H][8192] fp32
//   p1: partial[bh][split][129][128] = sum_n v[d][n]*relu(k[e][n])
//       m97-style: fp32 tiles staged via global_load_lds (async, counted
//       vmcnt(8), raw s_barrier), relu+bf16-cvt at fragment-read time.
//   p2: reduce -> vk fp32 -> split to vk_hi/vk_lo bf16 (+ den row fp32)
//   p3: out[d][n] = (sum_e (vk_hi+vk_lo)[d][e]*relu(q)[e][n]) / den[n]
// ---------------------------------------------------------------------------

typedef __attribute__((ext_vector_type(8))) short short8;
typedef __attribute__((ext_vector_type(4))) float f32x4;

__device__ inline unsigned short f2bf(float f) {
    unsigned u = __float_as_uint(f);
    u += 0x7FFFu + ((u >> 16) & 1u);            // RNE
    return (unsigned short)(u >> 16);
}
__device__ inline float bf2f(unsigned short h) {
    return __uint_as_float(((unsigned)h) << 16);
}
__device__ inline unsigned pk2(float a, float b) {
    return (unsigned)f2bf(a) | ((unsigned)f2bf(b) << 16);
}

__device__ __forceinline__ void gl_lds16(const float* g, char* l) {
    __builtin_amdgcn_global_load_lds(
        (const __attribute__((address_space(1))) void*)g,
        (__attribute__((address_space(3))) void*)l, 16, 0, 0);
}

// ============================ pass 1 =======================================
// 256 thr (2x2 waves), out tile 128d x 128e; TN=32-n fp32 tiles, dbuf LDS.
// LDS buf b at b*32768: V [128 rows][32 n] fp32 (16KB) at +0, K at +16384.
//   stage (linear dest): instr (w,ii) lds = b*32768 + arr*16384 + (w*4+ii)*1024
//     + lane*16 ; source row = (w*4+ii)*8 + (lane>>3),
//     source col-slot = (lane&7) ^ (lane>>3)  (pre-swizzled global source)
//   read (swizzled): logical (row, slot c) at byte row*128 + (c^(row&7))*16
__global__ __launch_bounds__(256, 2) void p1_vk(
    const float* __restrict__ K, const float* __restrict__ V,
    float* __restrict__ partial, int nsplit, int chunk)
{
    __shared__ char smem[65536];
    const int bh = blockIdx.y, split = blockIdx.x;
    const int t = threadIdx.x;
    const int lane = t & 63, w = t >> 6;
    const int dh = (w >> 1) << 6, eh = (w & 1) << 6;
    const int l15 = lane & 15, l4 = lane >> 4;
    const size_t base = (size_t)bh * (128 * 8192);
    const int n0 = split * chunk;
    const int niter = chunk >> 5;

    // per-lane stage source (tile-invariant part)
    const int srow = lane >> 3;                    // 0..7
    const int scol = ((lane & 7) ^ srow) << 2;     // pre-swizzled fp32 col
    const float* Vs = V + base + (size_t)(w * 32 + srow) * 8192 + n0 + scol;
    const float* Ks = K + base + (size_t)(w * 32 + srow) * 8192 + n0 + scol;
    char* lwb = smem + w * 4096;                   // this wave's staging slice

    f32x4 acc[4][4];
#pragma unroll
    for (int i = 0; i < 4; ++i)
#pragma unroll
        for (int j = 0; j < 4; ++j)
            acc[i][j] = (f32x4){0.f, 0.f, 0.f, 0.f};
    float kp[4] = {0.f, 0.f, 0.f, 0.f};

    auto stage = [&](int it, int buf) {
        const int nt = it << 5;
        char* lb = lwb + (buf << 15);
#pragma unroll
        for (int ii = 0; ii < 4; ++ii)
            gl_lds16(Vs + (size_t)(ii * 8) * 8192 + nt, lb + ii * 1024);
#pragma unroll
        for (int ii = 0; ii < 4; ++ii)
            gl_lds16(Ks + (size_t)(ii * 8) * 8192 + nt, lb + 16384 + ii * 1024);
    };

    auto compute = [&](int buf) {
        const char* bV = smem + (buf << 15);
        const char* bK = bV + 16384;
        short8 Bf[4];
#pragma unroll
        for (int j = 0; j < 4; ++j) {
            const int er = eh + (j << 4) + l15;
            const int rb = er * 128, sw = (er & 7) << 4;
            float4 f0 = *(const float4*)(bK + rb + ((((l4 << 1) + 0) << 4) ^ sw));
            float4 f1 = *(const float4*)(bK + rb + ((((l4 << 1) + 1) << 4) ^ sw));
            f0.x = fmaxf(f0.x, 0.f); f0.y = fmaxf(f0.y, 0.f);
            f0.z = fmaxf(f0.z, 0.f); f0.w = fmaxf(f0.w, 0.f);
            f1.x = fmaxf(f1.x, 0.f); f1.y = fmaxf(f1.y, 0.f);
            f1.z = fmaxf(f1.z, 0.f); f1.w = fmaxf(f1.w, 0.f);
            if (w < 2)   // waves 0,1 cover all e exactly once -> den row
                kp[j] += (f0.x + f0.y + f0.z + f0.w) + (f1.x + f1.y + f1.z + f1.w);
            union { unsigned u[4]; short8 s; } r;
            r.u[0] = pk2(f0.x, f0.y); r.u[1] = pk2(f0.z, f0.w);
            r.u[2] = pk2(f1.x, f1.y); r.u[3] = pk2(f1.z, f1.w);
            Bf[j] = r.s;
        }
#pragma unroll
        for (int i4 = 0; i4 < 4; ++i4) {
            const int dr = dh + (i4 << 4) + l15;
            const int rb = dr * 128, sw = (dr & 7) << 4;
            const float4 f0 = *(const float4*)(bV + rb + ((((l4 << 1) + 0) << 4) ^ sw));
            const float4 f1 = *(const float4*)(bV + rb + ((((l4 << 1) + 1) << 4) ^ sw));
            union { unsigned u[4]; short8 s; } r;
            r.u[0] = pk2(f0.x, f0.y); r.u[1] = pk2(f0.z, f0.w);
            r.u[2] = pk2(f1.x, f1.y); r.u[3] = pk2(f1.z, f1.w);
#pragma unroll
            for (int j = 0; j < 4; ++j)
                acc[i4][j] = __builtin_amdgcn_mfma_f32_16x16x32_bf16(
                        r.s, Bf[j], acc[i4][j], 0, 0, 0);
        }
    };

    // ---- pipelined main loop: 2 tiles in flight, counted vmcnt ----
    stage(0, 0);
    stage(1, 1);
    for (int it = 0; it < niter; ++it) {
        if (it + 1 < niter) asm volatile("s_waitcnt vmcnt(8)" ::: "memory");
        else                asm volatile("s_waitcnt vmcnt(0)" ::: "memory");
        __builtin_amdgcn_s_barrier();
        __builtin_amdgcn_sched_barrier(0);
        compute(it & 1);
        asm volatile("s_waitcnt lgkmcnt(0)" ::: "memory");
        __builtin_amdgcn_s_barrier();
        __builtin_amdgcn_sched_barrier(0);
        if (it + 2 < niter) stage(it + 2, it & 1);
    }
    asm volatile("s_waitcnt vmcnt(0)" ::: "memory");
    __syncthreads();

    // ---- den-row reduce via LDS overlay ----
    float* krd = (float*)smem;
    if (w < 2) {
#pragma unroll
        for (int j = 0; j < 4; ++j)
            krd[((w << 6) + (j << 4) + l15) * 4 + l4] = kp[j];
    }
    __syncthreads();

    float* p = partial + (size_t)(bh * nsplit + split) * 16512;
#pragma unroll
    for (int i = 0; i < 4; ++i)
#pragma unroll
        for (int j = 0; j < 4; ++j)
#pragma unroll
            for (int jj = 0; jj < 4; ++jj)
                p[(dh + (i << 4) + (l4 << 2) + jj) * 128 + eh + (j << 4) + l15] = acc[i][j][jj];
    if (t < 128)
        p[16384 + t] = krd[t * 4] + krd[t * 4 + 1] + krd[t * 4 + 2] + krd[t * 4 + 3];
}

// ============================ pass 2 =======================================
__global__ __launch_bounds__(256) void p2_reduce(
    const float* __restrict__ partial, unsigned short* __restrict__ vkhi,
    unsigned short* __restrict__ vklo, float* __restrict__ vkden, int nsplit)
{
    const int t = blockIdx.x * 256 + threadIdx.x;
    if (t >= 32 * 129 * 128) return;
    const int bh = t / 16512, rc = t % 16512;
    const int d = rc >> 7, e = rc & 127;
    float s = 0.f;
    for (int i = 0; i < nsplit; ++i)
        s += partial[(size_t)(bh * nsplit + i) * 16512 + rc];
    if (d < 128) {
        const size_t off = (size_t)bh * 16384 + (e >> 5) * 4096 + d * 32 + (e & 31);
        const unsigned short h = f2bf(s);
        vkhi[off] = h;
        vklo[off] = f2bf(s - bf2f(h));
    } else {
        vkden[bh * 128 + e] = s;
    }
}

// ============================ pass 3 =======================================
#define VKH 0
#define VKL 10240
#define SQO 20480
#define DEN 40960
#define VKD 41984
__global__ __launch_bounds__(256, 2) void p3_out(
    const float* __restrict__ Q, const unsigned short* __restrict__ vkhi,
    const unsigned short* __restrict__ vklo, const float* __restrict__ vkden,
    float* __restrict__ out)
{
    __shared__ char smem[42496];
    const int bh = blockIdx.y;
    const int b = bh >> 3, h = bh & 7;
    const int n0 = blockIdx.x << 8;
    const int t = threadIdx.x;
    const int lane = t & 63, w = t >> 6;
    const int l15 = lane & 15, l4 = lane >> 4;
    const int wn = w << 6;

    if (t < 128) ((float*)(smem + VKD))[t] = vkden[bh * 128 + t];
    __syncthreads();

    const float* qb = Q + (size_t)bh * (128 * 8192) + n0 + t;   // this thread's n column
    const float* vkd = (const float*)(smem + VKD);
    const unsigned short* ghb = vkhi + (size_t)bh * 16384;
    const unsigned short* glb = vklo + (size_t)bh * 16384;

    f32x4 acc[8][4];
#pragma unroll
    for (int i = 0; i < 8; ++i)
#pragma unroll
        for (int j = 0; j < 4; ++j)
            acc[i][j] = (f32x4){0.f, 0.f, 0.f, 0.f};
    float den = 0.f;

    for (int ek = 0; ek < 4; ++ek) {
        const int e0 = ek << 5;
#pragma unroll
        for (int l = 0; l < 2; ++l) {
            const int s = t + (l << 8);
            const int d = s >> 2, c = s & 3;
            const int loff = d * 80 + c * 16;
            *(uint4*)(smem + VKH + loff) = *(const uint4*)(ghb + ek * 4096 + s * 8);
            *(uint4*)(smem + VKL + loff) = *(const uint4*)(glb + ek * 4096 + s * 8);
        }
#pragma unroll
        for (int sub = 0; sub < 4; ++sub) {
            const int j0 = e0 + (sub << 3);
            float vq[8];
#pragma unroll
            for (int m = 0; m < 8; ++m) vq[m] = qb[(size_t)(j0 + m) * 8192];
#pragma unroll
            for (int m = 0; m < 8; ++m) {
                vq[m] = fmaxf(vq[m], 0.f);
                den = fmaf(vkd[j0 + m], vq[m], den);
            }
            uint4 pq;
            pq.x = pk2(vq[0], vq[1]); pq.y = pk2(vq[2], vq[3]);
            pq.z = pk2(vq[4], vq[5]); pq.w = pk2(vq[6], vq[7]);
            *(uint4*)(smem + SQO + t * 80 + (sub << 4)) = pq;
        }
        __syncthreads();
        short8 Bf[4];
#pragma unroll
        for (int fn = 0; fn < 4; ++fn) {
            const int nr = wn + (fn << 4) + l15;
            Bf[fn] = *(const short8*)(smem + SQO + nr * 80 + l4 * 16);
        }
#pragma unroll
        for (int fd = 0; fd < 8; ++fd) {
            const int dr = (fd << 4) + l15;
            const short8 Ah = *(const short8*)(smem + VKH + dr * 80 + l4 * 16);
            const short8 Al = *(const short8*)(smem + VKL + dr * 80 + l4 * 16);
#pragma unroll
            for (int fn = 0; fn < 4; ++fn) {
                acc[fd][fn] = __builtin_amdgcn_mfma_f32_16x16x32_bf16(Ah, Bf[fn], acc[fd][fn], 0, 0, 0);
                acc[fd][fn] = __builtin_amdgcn_mfma_f32_16x16x32_bf16(Al, Bf[fn], acc[fd][fn], 0, 0, 0);
            }
        }
        __syncthreads();
    }

    ((float*)(smem + DEN))[t] = den;
    __syncthreads();
    float rden[4];
#pragma unroll
    for (int fn = 0; fn < 4; ++fn)
        rden[fn] = 1.f / ((const float*)(smem + DEN))[wn + (fn << 4) + l15];

#pragma unroll
    for (int fd = 0; fd < 8; ++fd) {
#pragma unroll
        for (int fn = 0; fn < 4; ++fn) {
            const int n = n0 + wn + (fn << 4) + l15;
#pragma unroll
            for (int jj = 0; jj < 4; ++jj) {
                const int d = (fd << 4) + (l4 << 2) + jj;
                out[(((size_t)b * 128 + d) * 8 + h) * 8192 + n] = acc[fd][fn][jj] * rden[fn];
            }
        }
    }
}

// ============================ launch =======================================
extern "C" void kernel_launch(void* const* d_in, const int* in_sizes, int n_in,
                              void* d_out, int out_size, void* d_ws, size_t ws_size,
                              hipStream_t stream)
{
    const float* q = (const float*)d_in[0];
    const float* k = (const float*)d_in[1];
    const float* v = (const float*)d_in[2];
    float* out = (float*)d_out;
    char* ws = (char*)d_ws;

    int nsplit = 16;
    while (nsplit > 1 &&
           ((size_t)32 * nsplit * 16512 * 4 + (size_t)32 * 16384 * 2 * 2 + 32 * 128 * 4) > ws_size)
        nsplit >>= 1;
    const int chunk = 8192 / nsplit;

    float* partial = (float*)ws;
    unsigned short* vkhi = (unsigned short*)(ws + (size_t)32 * nsplit * 16512 * 4);
    unsigned short* vklo = vkhi + 32 * 16384;
    float* vkden = (float*)(vklo + 32 * 16384);

    p1_vk<<<dim3(nsplit, 32), 256, 0, stream>>>(k, v, partial, nsplit, chunk);
    p2_reduce<<<(32 * 129 * 128 + 255) / 256, 256, 0, stream>>>(partial, vkhi, vklo, vkden, nsplit);
    p3_out<<<dim3(32, 32), 256, 0, stream>>>(q, vkhi, vklo, vkden, out);
}